// Round 17
// baseline (504.125 us; speedup 1.0000x reference)
//
#include <hip/hip_runtime.h>
#include <hip/hip_bf16.h>
#include <cstdint>

#define T_STEPS 250
#define BATCH   256
#define NI      700
#define NH      1024
#define NO      20
#define BETAF   0.9f
#define KPAD    704          // 22 * 32
#define KT_N    22
#define KCAT    2112         // 3 * KPAD

typedef __attribute__((ext_vector_type(8))) short bf16x8;
typedef __attribute__((ext_vector_type(4))) float f32x4;

static __device__ __forceinline__ unsigned short f2bu(float x) {
    union { __hip_bfloat16 h; unsigned short u; } c;
    c.h = __float2bfloat16(x);
    return c.u;
}
static __device__ __forceinline__ float b2f(unsigned short u) {
    union { __hip_bfloat16 h; unsigned short u; } c;
    c.u = u;
    return __bfloat162float(c.h);
}

// ---------------------------------------------------------------------------
// K0: zero LIF state; W2T[h][o]; Bcat = [hi|mid|lo] bf16 split of W1,
//     padded K 700->704. LOCKED (only decomposition with pass evidence).
// ---------------------------------------------------------------------------
__global__ __launch_bounds__(256) void k0_init(const float* __restrict__ W1,
                                               const float* __restrict__ W2,
                                               float* __restrict__ W2T,
                                               float* __restrict__ mem1,
                                               unsigned short* __restrict__ Bcat) {
    int idx = blockIdx.x * 256 + threadIdx.x;
    if (idx < BATCH * NH) mem1[idx] = 0.f;
    if (idx < NH * NO) {
        int h = idx / NO, o = idx % NO;
        W2T[idx] = W2[o * NH + h];
    }
    if (idx < NH * KPAD) {
        int n = idx / KPAD, k = idx % KPAD;
        float w = (k < NI) ? W1[n * NI + k] : 0.f;
        unsigned short hu = f2bu(w);
        float r1 = w - b2f(hu);
        unsigned short mu = f2bu(r1);
        float r2 = r1 - b2f(mu);
        unsigned short lu = f2bu(r2);
        unsigned short* row = Bcat + (size_t)n * KCAT + k;
        row[0]        = hu;
        row[KPAD]     = mu;
        row[2 * KPAD] = lu;
    }
}

// ---------------------------------------------------------------------------
// K1: convert fp32 binary spikes [rows][700] -> bf16 [rows][704] (exact).
// ---------------------------------------------------------------------------
__global__ __launch_bounds__(256) void k1_cvt(const float* __restrict__ A,
                                              unsigned short* __restrict__ Abf,
                                              int rows) {
    int idx = blockIdx.x * 256 + threadIdx.x;   // quad index: 176 per row
    int r = idx / 176, q = idx - r * 176;
    if (r >= rows) return;
    int k = q * 4;
    ushort4 o = make_ushort4(0, 0, 0, 0);
    if (k < NI) {
        float4 v = *(const float4*)(A + (size_t)r * NI + k);
        o.x = f2bu(v.x); o.y = f2bu(v.y); o.z = f2bu(v.z); o.w = f2bu(v.w);
    }
    *(ushort4*)(Abf + (size_t)r * KPAD + k) = o;
}

// ---------------------------------------------------------------------------
// K2 v6: 256x128 / BK=32 / 8 waves / 80KB LDS / 2 blocks/CU, single heavy
//   phase per K-iter (R16-proven), with PING-PONG B FRAGMENTS to overlap
//   the LDS-read pipe with the MFMA pipe:
//     loadA; loadB->bA; { loadB->bB; 16 MFMA(bA) }; { loadB->bA; 16 MFMA(bB) };
//     16 MFMA(bA)
//   Each B-read issues under the previous MFMA cluster (no dependency,
//   different regs); compiler inserts fine-grained lgkmcnt. R16's single
//   live b[4] created a WAR chain (read waits on mm) that serialized the
//   pipes: measured 245us ~= LDS(110) + MFMA(133) SUM. Overlap targets max.
//   Accumulation order unchanged (kt asc, s=0,1,2 asc) -> cur1 BIT-IDENTICAL.
//   +16 VGPR (~80 total) still fits 128/wave at 4 waves/SIMD.
//   Schedule per iter: wait vmcnt(5); stage 5 loads -> buf^1; BAR;
//   compute (above); BAR. R4-proven 64B-row swizzle, rule-21 staging,
//   XCD-grouped bid swizzle.
// ---------------------------------------------------------------------------
__global__ __launch_bounds__(512, 4) void k2_fc1(const unsigned short* __restrict__ Abf,
                                                 const unsigned short* __restrict__ Bcat,
                                                 float* __restrict__ C) {
    __shared__ unsigned short As[2][256 * 32];      // 2 x 16 KB
    __shared__ unsigned short Bs[2][3][128 * 32];   // 2 x 3 x 8 KB
    const int tid  = threadIdx.x;
    const int lane = tid & 63;
    const int wv   = tid >> 6;
    const int wr   = wv >> 1;        // 0..3: wave row-quarter (64 rows)
    const int wc   = wv & 1;         // 0..1: wave col-half (64 cols)

    int nwg = gridDim.x, bid = blockIdx.x, w;
    if ((nwg & 7) == 0) w = (bid & 7) * (nwg >> 3) + (bid >> 3);
    else                w = bid;
    const int brow = (w >> 3) * 256;
    const int bn   = (w & 7) * 128;

    f32x4 acc[4][4];
#pragma unroll
    for (int i = 0; i < 4; ++i)
#pragma unroll
        for (int j = 0; j < 4; ++j) acc[i][j] = (f32x4){0.f, 0.f, 0.f, 0.f};

    const unsigned short* Ab = Abf + (size_t)brow * KPAD;
    const unsigned short* Bb = Bcat + (size_t)bn * KCAT;

    // A tile: 256x32 = 1024 16B chunks, 2 gload_lds/thread.
    auto stageA = [&](int kcol, unsigned short* tile) {
#pragma unroll
        for (int j = 0; j < 2; ++j) {
            int c   = j * 512 + wv * 64 + lane;
            int row = c >> 2;
            int lk  = ((c & 3) ^ ((row >> 1) & 3)) * 8;
            const unsigned short* src = Ab + (size_t)row * KPAD + kcol + lk;
            __builtin_amdgcn_global_load_lds(
                (const __attribute__((address_space(1))) void*)src,
                (__attribute__((address_space(3))) void*)(tile + (size_t)(j * 512 + wv * 64) * 8),
                16, 0, 0);
        }
    };
    // B split tile: 128x32 = 512 chunks, 1 gload_lds/thread.
    auto stageB = [&](int kcol, unsigned short* tile) {
        int c   = wv * 64 + lane;
        int row = c >> 2;
        int lk  = ((c & 3) ^ ((row >> 1) & 3)) * 8;
        const unsigned short* src = Bb + (size_t)row * KCAT + kcol + lk;
        __builtin_amdgcn_global_load_lds(
            (const __attribute__((address_space(1))) void*)src,
            (__attribute__((address_space(3))) void*)(tile + (size_t)(wv * 64) * 8),
            16, 0, 0);
    };

    const int frow = lane & 15;
    const int fsl  = (((lane >> 4) & 3) ^ ((frow >> 1) & 3)) * 8;

    bf16x8 a[4], bA[4], bB[4];
    auto loadA = [&](const unsigned short* Ac) {
#pragma unroll
        for (int i = 0; i < 4; ++i)
            a[i] = *(const bf16x8*)&Ac[(wr * 64 + i * 16 + frow) * 32 + fsl];
    };
    auto loadB = [&](const unsigned short* Bc, bf16x8* b) {
#pragma unroll
        for (int j = 0; j < 4; ++j)
            b[j] = *(const bf16x8*)&Bc[(wc * 64 + j * 16 + frow) * 32 + fsl];
    };
    auto mm = [&](const bf16x8* b) {
#pragma unroll
        for (int j = 0; j < 4; ++j)
#pragma unroll
            for (int i = 0; i < 4; ++i)
                acc[i][j] = __builtin_amdgcn_mfma_f32_16x16x32_bf16(
                    a[i], b[j], acc[i][j], 0, 0, 0);
    };

    // prologue: stage K-tile 0 (A + 3 B-splits), full drain, barrier.
    stageA(0, As[0]);
#pragma unroll
    for (int s = 0; s < 3; ++s) stageB(s * KPAD, Bs[0][s]);
    asm volatile("s_waitcnt vmcnt(0)" ::: "memory");
    __builtin_amdgcn_s_barrier();

    for (int kt = 0; kt < KT_N; ++kt) {
        const int buf = kt & 1;
        const bool st = (kt + 1 < KT_N);
        const int kc = (kt + 1) * 32;

        // single heavy phase per iter
        if (st) {
            asm volatile("s_waitcnt vmcnt(5)" ::: "memory");  // cur tile landed
            stageA(kc, As[buf ^ 1]);
            stageB(kc, Bs[buf ^ 1][0]);
            stageB(KPAD + kc, Bs[buf ^ 1][1]);
            stageB(2 * KPAD + kc, Bs[buf ^ 1][2]);
        } else {
            asm volatile("s_waitcnt vmcnt(0)" ::: "memory");  // last tile
        }
        __builtin_amdgcn_s_barrier();

        loadA(As[buf]);
        loadB(Bs[buf][0], bA);
        __builtin_amdgcn_s_setprio(1);
        loadB(Bs[buf][1], bB);    // issues under mm(bA)
        mm(bA);                   // s = 0
        loadB(Bs[buf][2], bA);    // issues under mm(bB)
        mm(bB);                   // s = 1
        mm(bA);                   // s = 2
        __builtin_amdgcn_s_setprio(0);
        __builtin_amdgcn_s_barrier();
    }

    // C/D layout: col = lane&15, row = (lane>>4)*4 + q.
#pragma unroll
    for (int i = 0; i < 4; ++i) {
#pragma unroll
        for (int j = 0; j < 4; ++j) {
            int col  = bn + wc * 64 + j * 16 + (lane & 15);
            int row0 = brow + wr * 64 + i * 16 + ((lane >> 4) << 2);
#pragma unroll
            for (int q = 0; q < 4; ++q)
                C[(size_t)(row0 + q) * NH + col] = acc[i][j][q];
        }
    }
}

// ---------------------------------------------------------------------------
// K3: LIF scan, 2 h per thread (float2 loads), 4-deep prefetch,
//   j-interleaved spike words (R12-proven). Bit-identical LIF arithmetic.
// ---------------------------------------------------------------------------
__global__ __launch_bounds__(256) void k3_lif(const float* __restrict__ cur1,
                                              float* __restrict__ mem1,
                                              unsigned long long* __restrict__ bits,
                                              int TC) {
    const int b    = blockIdx.x >> 1;
    const int half = blockIdx.x & 1;
    const int wv   = threadIdx.x >> 6;
    const int lane = threadIdx.x & 63;
    const int h    = half * 512 + wv * 128 + lane * 2;
    const size_t S = (size_t)BATCH * NH;
    const float* p = cur1 + (size_t)b * NH + h;
    unsigned long long* bp = bits + (size_t)b * 16 + (half * 4 + wv) * 2;
    const bool lead = lane == 0;

    float2 mm = *(const float2*)(mem1 + b * NH + h);
    float m0 = mm.x, m1 = mm.y;

    auto ld = [&](int t) -> float2 {
        int tt = t < TC ? t : TC - 1;
        return *(const float2*)(p + (size_t)tt * S);
    };

#define K3_STEP(cv, t)                                                         \
    {                                                                          \
        float r0 = (m0 > 1.f) ? 1.f : 0.f;                                     \
        m0 = fmaf(BETAF, m0, (cv).x) - r0;                                     \
        float r1 = (m1 > 1.f) ? 1.f : 0.f;                                     \
        m1 = fmaf(BETAF, m1, (cv).y) - r1;                                     \
        unsigned long long w0 = __ballot(m0 > 1.f);                            \
        unsigned long long w1 = __ballot(m1 > 1.f);                            \
        if (lead) {                                                            \
            ulonglong2 v; v.x = w0; v.y = w1;                                  \
            *(ulonglong2*)(bp + (size_t)(t) * (BATCH * 16)) = v;               \
        }                                                                      \
    }

    float2 c0 = ld(0), c1 = ld(1), c2 = ld(2), c3 = ld(3);
    int tc = 0;
    for (; tc + 4 <= TC; tc += 4) {
        K3_STEP(c0, tc + 0); c0 = ld(tc + 4);
        K3_STEP(c1, tc + 1); c1 = ld(tc + 5);
        K3_STEP(c2, tc + 2); c2 = ld(tc + 6);
        K3_STEP(c3, tc + 3); c3 = ld(tc + 7);
    }
    for (; tc < TC; ++tc) { float2 c = ld(tc); K3_STEP(c, tc); }
#undef K3_STEP
    float2 mo; mo.x = m0; mo.y = m1;
    *(float2*)(mem1 + b * NH + h) = mo;
}

// ---------------------------------------------------------------------------
// K4: fc2 sparse gather, one wave per (t,b) row, 4 rows/block.
//   Word i maps h = (i>>1)*128 + 2*bit + (i&1).
// ---------------------------------------------------------------------------
__global__ __launch_bounds__(256) void k4_fc2(const unsigned long long* __restrict__ bits,
                                              const float* __restrict__ W2T,
                                              float* __restrict__ cur2) {
    int row  = blockIdx.x * 4 + (threadIdx.x >> 6);
    int lane = threadIdx.x & 63;
    bool act = lane < NO;
    unsigned long long mv = (lane < 16) ? bits[(size_t)row * 16 + lane] : 0ULL;
    const float* W = W2T + (act ? lane : 0);
    float p0 = 0.f, p1 = 0.f;
#pragma unroll
    for (int i = 0; i < 16; ++i) {
        unsigned long long m = __shfl(mv, i);
        int base = (i >> 1) * 128 + (i & 1);
        while (m) {
            int  b0 = __ffsll(m) - 1;            m &= m - 1;
            bool v1 = m != 0;
            int  b1 = v1 ? __ffsll(m) - 1 : 0;   m &= m - 1;
            float w0 = W[(base + 2 * b0) * NO];
            float w1 = W[(base + 2 * b1) * NO];
            p0 += w0;
            p1 += v1 ? w1 : 0.f;
        }
    }
    if (act) cur2[(size_t)row * NO + lane] = p0 + p1;
}

// ---------------------------------------------------------------------------
// K5: leaky readout + softmax; 128 blocks x 64 threads.
// ---------------------------------------------------------------------------
__global__ __launch_bounds__(64) void k5_readout(const float* __restrict__ cur2,
                                                 float* __restrict__ out_mem,
                                                 float* __restrict__ out_sm) {
    int b = blockIdx.x * 2 + (threadIdx.x >> 5);
    int o = threadIdx.x & 31;
    bool act = o < NO;
    const float* p = cur2 + (size_t)b * NO + (act ? o : 0);
    float mem = 0.f;
    float nxt = p[0];
    for (int t = 0; t < T_STEPS; ++t) {
        float c = nxt;
        if (t + 1 < T_STEPS) nxt = p[(size_t)(t + 1) * BATCH * NO];
        mem = fmaf(BETAF, mem, c);
        float e = act ? __expf(mem) : 0.f;
        float s = e;
#pragma unroll
        for (int off = 16; off; off >>= 1) s += __shfl_xor(s, off, 32);
        if (act) {
            int base = (t * BATCH + b) * NO;
            out_mem[base + o] = mem;
            out_sm[base + o] = __fdividef(e, s);
        }
    }
}

// ---------------------------------------------------------------------------
extern "C" void kernel_launch(void* const* d_in, const int* in_sizes, int n_in,
                              void* d_out, int out_size, void* d_ws, size_t ws_size,
                              hipStream_t stream) {
    const float* spikes = (const float*)d_in[0];   // [250,256,700]
    const float* W1     = (const float*)d_in[1];   // [1024,700]
    const float* W2     = (const float*)d_in[2];   // [20,1024]
    float* out_mem = (float*)d_out;                              // [250,256,20]
    float* out_sm  = out_mem + (size_t)T_STEPS * BATCH * NO;     // [250,256,20]

    char* ws = (char*)d_ws;
    size_t off = 0;
    auto alloc = [&](size_t bytes) -> char* {
        off = (off + 255) & ~(size_t)255;
        char* p = ws + off;
        off += bytes;
        return p;
    };
    float*          W2T  = (float*)alloc((size_t)NH * NO * 4);
    float*          mem1 = (float*)alloc((size_t)BATCH * NH * 4);
    float*          cur2 = (float*)alloc((size_t)T_STEPS * BATCH * NO * 4);
    unsigned short* Bcat = (unsigned short*)alloc((size_t)NH * KCAT * 2);

    // T-chunking: per step need cur1 (1 MB) + Abf (352 KB) + bits (32 KB).
    size_t fixed = (off + 255) & ~(size_t)255;
    size_t rem = ws_size > fixed ? ws_size - fixed : 0;
    size_t per_t = (size_t)BATCH * NH * 4 + (size_t)BATCH * KPAD * 2
                 + (size_t)BATCH * 16 * 8 + 768;
    int TC = (int)(rem / per_t);
    if (TC > T_STEPS) TC = T_STEPS;
    if (TC < 1) TC = 1;
    float*              cur1 = (float*)alloc((size_t)TC * BATCH * NH * 4);
    unsigned short*     Abf  = (unsigned short*)alloc((size_t)TC * BATCH * KPAD * 2);
    unsigned long long* bits = (unsigned long long*)alloc((size_t)TC * BATCH * 16 * 8);

    k0_init<<<(NH * KPAD + 255) / 256, 256, 0, stream>>>(W1, W2, W2T, mem1, Bcat);

    for (int t0 = 0; t0 < T_STEPS; t0 += TC) {
        int tc = T_STEPS - t0 < TC ? T_STEPS - t0 : TC;
        int rows = tc * BATCH;
        k1_cvt<<<(rows * 176 + 255) / 256, 256, 0, stream>>>(
            spikes + (size_t)t0 * BATCH * NI, Abf, rows);
        int nwg = (rows / 256) * 8;   // 256-row m-tiles x 8 n-tiles (128 cols)
        k2_fc1<<<nwg, 512, 0, stream>>>(Abf, Bcat, cur1);
        k3_lif<<<512, 256, 0, stream>>>(cur1, mem1, bits, tc);
        k4_fc2<<<rows / 4, 256, 0, stream>>>(bits, W2T, cur2 + (size_t)t0 * BATCH * NO);
    }

    k5_readout<<<128, 64, 0, stream>>>(cur2, out_mem, out_sm);
}